// Round 7
// baseline (923.335 us; speedup 1.0000x reference)
//
#include <hip/hip_runtime.h>
#include <hip/hip_bf16.h>
#include <hip/hip_fp16.h>

#define H 2048
#define E 8
#define DFF 8192
#define NTOK 4096
#define NB 4  // H/512 scale blocks

typedef _Float16 f16x8 __attribute__((ext_vector_type(8)));
typedef _Float16 f16x4 __attribute__((ext_vector_type(4)));
typedef float f32x4 __attribute__((ext_vector_type(4)));

#define AS1 __attribute__((address_space(1)))
#define AS3 __attribute__((address_space(3)))

__device__ __forceinline__ void gl_lds16(const void* g, void* l) {
    __builtin_amdgcn_global_load_lds((const AS1 unsigned int*)g,
                                     (AS3 unsigned int*)l, 16, 0, 0);
}

__device__ __forceinline__ float gelu_f(float x) {
    // jax.nn.gelu approximate=True (tanh), exp2-based tanh
    float u = 0.7978845608028654f * x * (1.0f + 0.044715f * x * x);
    float t = fabsf(u);
    float e = __expf(-2.0f * t);
    float th = (1.0f - e) / (1.0f + e);
    th = copysignf(th, u);
    return 0.5f * x * (1.0f + th);
}

// ---------------- router (fp32) + x -> fp16 cast ----------------
__global__ __launch_bounds__(256) void router_cast_kernel(
    const float* __restrict__ x, const float* __restrict__ rw,
    float* __restrict__ probs, _Float16* __restrict__ xh)
{
    int n = blockIdx.x, t = threadIdx.x;
    float acc[E];
#pragma unroll
    for (int e = 0; e < E; ++e) acc[e] = 0.f;
    const float* xr = x + (size_t)n * H;
#pragma unroll
    for (int k = 0; k < H / 256; ++k) {
        int h = t + k * 256;
        float xv = xr[h];
        xh[(size_t)n * H + h] = (_Float16)xv;
        const float4* r4 = reinterpret_cast<const float4*>(rw + (size_t)h * E);
        float4 a = r4[0], b = r4[1];
        acc[0] += xv * a.x; acc[1] += xv * a.y; acc[2] += xv * a.z; acc[3] += xv * a.w;
        acc[4] += xv * b.x; acc[5] += xv * b.y; acc[6] += xv * b.z; acc[7] += xv * b.w;
    }
#pragma unroll
    for (int e = 0; e < E; ++e) {
        float v = acc[e];
#pragma unroll
        for (int o = 32; o > 0; o >>= 1) v += __shfl_down(v, o, 64);
        acc[e] = v;
    }
    __shared__ float red[4][E];
    int wave = t >> 6, lane = t & 63;
    if (lane == 0) {
#pragma unroll
        for (int e = 0; e < E; ++e) red[wave][e] = acc[e];
    }
    __syncthreads();
    if (t == 0) {
        float lg[E];
        float mx = -1e30f;
#pragma unroll
        for (int e = 0; e < E; ++e) {
            lg[e] = red[0][e] + red[1][e] + red[2][e] + red[3][e];
            mx = fmaxf(mx, lg[e]);
        }
        float s = 0.f;
#pragma unroll
        for (int e = 0; e < E; ++e) { lg[e] = expf(lg[e] - mx); s += lg[e]; }
        float inv = 1.f / s;
#pragma unroll
        for (int e = 0; e < E; ++e) {
            float p = lg[e] * inv;
            p = __half2float(__float2half(p));  // fp16 round-trip as in reference
            probs[(size_t)n * E + e] = p;
        }
    }
}

// ---------------- transpose + cast fp32 [R,C] -> fp16 [C,R] ----------------
__global__ __launch_bounds__(256) void transpose_cast_kernel(
    const float* __restrict__ src, _Float16* __restrict__ dst, int R, int C)
{
    __shared__ float tile[32][33];
    int tx = threadIdx.x & 31, ty = threadIdx.x >> 5;
    int c0 = blockIdx.x * 32, r0 = blockIdx.y * 32;
#pragma unroll
    for (int i = ty; i < 32; i += 8)
        tile[i][tx] = src[(size_t)(r0 + i) * C + c0 + tx];
    __syncthreads();
#pragma unroll
    for (int i = ty; i < 32; i += 8)
        dst[(size_t)(c0 + i) * R + r0 + tx] = (_Float16)tile[tx][i];
}

// ---------------- NF4 dequant + expert mix -> moe (fp32) ----------------
__global__ __launch_bounds__(256) void moe_kernel(
    const int* __restrict__ nf4, const float* __restrict__ mean,
    const float* __restrict__ stdv, const float* __restrict__ cb,
    const float* __restrict__ probs, float* __restrict__ moe)
{
    int n = blockIdx.x, t = threadIdx.x;
    __shared__ float cbl[32];       // 2 copies of 16-entry codebook
    __shared__ float ps[E][NB];     // prob*std
    __shared__ float cmean[NB];     // sum_e prob*mean
    if (t < 16) { float v = cb[t]; cbl[t] = v; cbl[t + 16] = v; }
    else if (t >= 32 && t < 64) {
        int e = (t - 32) >> 2, b = t & 3;
        ps[e][b] = probs[(size_t)n * E + e] * stdv[((size_t)n * E + e) * NB + b];
    } else if (t >= 64 && t < 68) {
        int b = t - 64; float s = 0.f;
        for (int e = 0; e < E; ++e)
            s += probs[(size_t)n * E + e] * mean[((size_t)n * E + e) * NB + b];
        cmean[b] = s;
    }
    __syncthreads();
    int cboff = (t & 1) << 4;
    const int* w = nf4 + (size_t)n * (E * H / 2);
    float2* outp = reinterpret_cast<float2*>(moe + (size_t)n * H);
#pragma unroll
    for (int k = 0; k < 4; ++k) {    // b = (t + k*256)>>8 == k (wave-uniform)
        int j = t + k * 256;
        float psr[E];
#pragma unroll
        for (int e = 0; e < E; ++e) psr[e] = ps[e][k];
        float cm = cmean[k];
        float aL = cm, aH = cm;
#pragma unroll
        for (int e = 0; e < E; ++e) {
            int word = w[e * (H / 2) + j];
            aL += psr[e] * cbl[(word & 15) + cboff];
            aH += psr[e] * cbl[((word >> 4) & 15) + cboff];
        }
        outp[j] = make_float2(aL, aH);
    }
}

// ---------------- fp16 MFMA GEMM: C = A[M,K] * Bt[N,K]^T ----------------
// Double-buffered LDS pipeline (vmcnt(4) keeps prefetch in flight across the
// barrier). XCD swizzles sized to keep the per-XCD B-band + A strip UNDER the
// 4 MB L2 (round-6 fix: previous bands equalled 4 MB -> thrash):
//  SWZ 0 (gemm1, gx=64): band = 4 x-blocks (2 MB B + 0.5 MB A), 2 super-cols.
//  SWZ 1 (gemm2, gx=16, split-K=2): band = 2 x-blocks of half-K (2 MB B +
//         1 MB A), k-slice = chunk>>6; partial written per slice.
// EPI 0: out = f16(gelu(acc))   EPI 2: partial fp16 at part*NTOK*N
template <int EPI, int SWZ, typename OT>
__global__ __launch_bounds__(256, 4) void gemm_bt_kernel(
    const _Float16* __restrict__ A, const _Float16* __restrict__ Bt,
    OT* __restrict__ outb, int K, int kLen, int N)
{
    __shared__ uint4 lds_u4[2048];   // 32 KB: buf0/buf1
    char* lds = (char*)lds_u4;

    int t = threadIdx.x;
    int id = blockIdx.x;
    int xcd = id & 7, chunk = id >> 3;
    int bx, by, kBase = 0;
    size_t partOff = 0;
    if constexpr (SWZ == 0) {
        int sc = chunk >> 7, rem = chunk & 127;
        bx = sc * 32 + xcd * 4 + (rem & 3);
        by = rem >> 2;
    } else {
        int ks = chunk >> 6, rem = chunk & 63;
        bx = xcd * 2 + (rem & 1);
        by = rem >> 1;
        kBase = ks * kLen;
        partOff = (size_t)ks * NTOK * N;
    }
    int m0 = by * 128, n0 = bx * 128;

    int r = t & 127, s0 = t >> 7;            // staging row / k-seg
    const unsigned short* pA = (const unsigned short*)A + (size_t)(m0 + r) * K + kBase + s0 * 8;
    const unsigned short* pB = (const unsigned short*)Bt + (size_t)(n0 + r) * K + kBase + s0 * 8;
    unsigned dst0 = (unsigned)t * 16, dst1 = (unsigned)t * 16 + 4096;

    int lane = t & 63, wave = t >> 6;
    int wm = (wave & 1) * 64, wn = (wave >> 1) * 64;
    int q = lane >> 4, m16 = lane & 15;

    unsigned aoff[4], boff[4];
#pragma unroll
    for (int i = 0; i < 4; ++i) aoff[i] = (unsigned)(q * 128 + wm + i * 16 + m16) * 16;
#pragma unroll
    for (int j = 0; j < 4; ++j) boff[j] = 8192u + (unsigned)(q * 128 + wn + j * 16 + m16) * 16;

    f32x4 acc[4][4] = {};

    gl_lds16(pA,      lds + dst0);
    gl_lds16(pA + 16, lds + dst1);
    gl_lds16(pB,      lds + 8192 + dst0);
    gl_lds16(pB + 16, lds + 8192 + dst1);

    unsigned cur = 0;
    for (int k0 = 0; k0 < kLen; k0 += 32) {
        unsigned nxt = cur ^ 16384u;
        if (k0 + 32 < kLen) {
            gl_lds16(pA + k0 + 32, lds + nxt + dst0);
            gl_lds16(pA + k0 + 48, lds + nxt + dst1);
            gl_lds16(pB + k0 + 32, lds + nxt + 8192 + dst0);
            gl_lds16(pB + k0 + 48, lds + nxt + 8192 + dst1);
            asm volatile("s_waitcnt vmcnt(4)" ::: "memory");
        } else {
            asm volatile("s_waitcnt vmcnt(0)" ::: "memory");
        }
        asm volatile("s_barrier" ::: "memory");

        f16x8 af[4], bfr[4];
#pragma unroll
        for (int i = 0; i < 4; ++i) af[i] = *(const f16x8*)(lds + cur + aoff[i]);
#pragma unroll
        for (int j = 0; j < 4; ++j) bfr[j] = *(const f16x8*)(lds + cur + boff[j]);
#pragma unroll
        for (int i = 0; i < 4; ++i)
#pragma unroll
            for (int j = 0; j < 4; ++j)
                acc[i][j] = __builtin_amdgcn_mfma_f32_16x16x32_f16(af[i], bfr[j], acc[i][j], 0, 0, 0);

        asm volatile("s_waitcnt lgkmcnt(0)" ::: "memory");
        asm volatile("s_barrier" ::: "memory");
        cur = nxt;
    }

#pragma unroll
    for (int i = 0; i < 4; ++i)
#pragma unroll
        for (int j = 0; j < 4; ++j) {
            int row = m0 + wm + i * 16 + q * 4;
            int col = n0 + wn + j * 16 + m16;
#pragma unroll
            for (int rix = 0; rix < 4; ++rix) {
                float v = acc[i][j][rix];
                size_t o = (size_t)(row + rix) * N + col;
                if constexpr (EPI == 0) {
                    outb[o] = (OT)gelu_f(v);
                } else {
                    outb[partOff + o] = (OT)v;
                }
            }
        }
}

// ---------------- out = p0 + p1 + moe ----------------
__global__ __launch_bounds__(256) void reduce_kernel(
    const _Float16* __restrict__ p, const float* __restrict__ moe,
    float* __restrict__ out)
{
    size_t i = ((size_t)blockIdx.x * 256 + threadIdx.x) * 4;
    f16x4 a = *(const f16x4*)(p + i);
    f16x4 b = *(const f16x4*)(p + (size_t)NTOK * H + i);
    float4 m = *(const float4*)(moe + i);
    float4 o;
    o.x = m.x + (float)a[0] + (float)b[0];
    o.y = m.y + (float)a[1] + (float)b[1];
    o.z = m.z + (float)a[2] + (float)b[2];
    o.w = m.w + (float)a[3] + (float)b[3];
    *(float4*)(out + i) = o;
}

extern "C" void kernel_launch(void* const* d_in, const int* in_sizes, int n_in,
                              void* d_out, int out_size, void* d_ws, size_t ws_size,
                              hipStream_t stream) {
    const float* x    = (const float*)d_in[0];
    const float* rw   = (const float*)d_in[1];
    const int*   nf4  = (const int*)d_in[2];
    const float* mean = (const float*)d_in[3];
    const float* stdv = (const float*)d_in[4];
    const float* cb   = (const float*)d_in[5];
    const float* w1   = (const float*)d_in[6];
    const float* w2   = (const float*)d_in[7];
    float* out = (float*)d_out;   // reference output dtype is float32

    char* ws = (char*)d_ws;
    float* probs      = (float*)ws;                          // 128 KB
    float* moe        = (float*)(ws + 131072);               // 32 MB
    _Float16* xh      = (_Float16*)(ws + 33685504);          // 16 MB  [NTOK,H]
    _Float16* w1t     = (_Float16*)(ws + 50462720);          // 32 MB  [DFF,H]
    _Float16* w2t     = (_Float16*)(ws + 84017152);          // 32 MB  [H,DFF]
    _Float16* hid     = (_Float16*)(ws + 117571584);         // 64 MB  [NTOK,DFF]
    // split-K partials [2][NTOK,H] fp16 = 32 MB, overlaid on xh+w1t (both
    // dead after gemm1; w2t/hid/moe stay live)
    _Float16* parts   = (_Float16*)(ws + 33685504);

    router_cast_kernel<<<NTOK, 256, 0, stream>>>(x, rw, probs, xh);
    transpose_cast_kernel<<<dim3(DFF / 32, H / 32), 256, 0, stream>>>(w1, w1t, H, DFF);
    transpose_cast_kernel<<<dim3(H / 32, DFF / 32), 256, 0, stream>>>(w2, w2t, DFF, H);
    moe_kernel<<<NTOK, 256, 0, stream>>>(nf4, mean, stdv, cb, probs, moe);
    // hidden = gelu(x @ w1):  A=xh [4096,2048], Bt=w1t [8192,2048], grid 2048
    gemm_bt_kernel<0, 0, _Float16><<<2048, 256, 0, stream>>>(xh, w1t, hid, H, H, DFF);
    // partials = hid @ w2 (split-K=2): A=hid [4096,8192], Bt=w2t [2048,8192], grid 1024
    gemm_bt_kernel<2, 1, _Float16><<<1024, 256, 0, stream>>>(hid, w2t, parts, DFF, DFF / 2, H);
    // out = p0 + p1 + moe
    reduce_kernel<<<NTOK * H / 1024, 256, 0, stream>>>(parts, moe, out);
}